// Round 1
// baseline (1706.038 us; speedup 1.0000x reference)
//
#include <hip/hip_runtime.h>
#include <hip/hip_bf16.h>
#include <cstdint>

#define B_ 256
#define T_ 512
#define F_ 128
#define H_ 128
#define G3_ 384
#define R_ 8
#define K_ 64

__device__ __forceinline__ float sigm(float x) { return 1.f / (1.f + __expf(-x)); }
__device__ __forceinline__ float tanh_f(float x) { return 1.f - 2.f / (1.f + __expf(2.f * x)); }

// C[m][n] = sum_k A[m][k] * W[n][k] + bias[n];  M = B*T, N = 384, K = 128
__global__ __launch_bounds__(256) void gemm_gi(const float* __restrict__ A,
                                               const float* __restrict__ W,
                                               const float* __restrict__ bias,
                                               float* __restrict__ C)
{
    __shared__ alignas(16) float As[32][68];
    __shared__ alignas(16) float Bs[32][68];
    const int tid = threadIdx.x;
    const int tx = tid & 15, ty = tid >> 4;
    const size_t m0 = (size_t)blockIdx.y * 64;
    const int n0 = blockIdx.x * 64;

    float acc[4][4] = {};

    for (int kb = 0; kb < 128; kb += 32) {
        #pragma unroll
        for (int it = 0; it < 2; ++it) {
            int idx = tid + it * 256;
            int row = idx >> 3, kq = idx & 7;
            float4 av = *(const float4*)(A + (m0 + row) * 128 + kb + kq * 4);
            As[kq * 4 + 0][row] = av.x; As[kq * 4 + 1][row] = av.y;
            As[kq * 4 + 2][row] = av.z; As[kq * 4 + 3][row] = av.w;
            float4 bv = *(const float4*)(W + (size_t)(n0 + row) * 128 + kb + kq * 4);
            Bs[kq * 4 + 0][row] = bv.x; Bs[kq * 4 + 1][row] = bv.y;
            Bs[kq * 4 + 2][row] = bv.z; Bs[kq * 4 + 3][row] = bv.w;
        }
        __syncthreads();
        #pragma unroll
        for (int k = 0; k < 32; ++k) {
            float4 a4 = *(const float4*)&As[k][ty * 4];
            float4 b4 = *(const float4*)&Bs[k][tx * 4];
            float a_[4] = {a4.x, a4.y, a4.z, a4.w};
            float b_[4] = {b4.x, b4.y, b4.z, b4.w};
            #pragma unroll
            for (int i = 0; i < 4; ++i)
                #pragma unroll
                for (int j = 0; j < 4; ++j)
                    acc[i][j] += a_[i] * b_[j];
        }
        __syncthreads();
    }

    float4 bb = *(const float4*)(bias + n0 + tx * 4);
    float bi[4] = {bb.x, bb.y, bb.z, bb.w};
    #pragma unroll
    for (int i = 0; i < 4; ++i) {
        float4 o;
        o.x = acc[i][0] + bi[0]; o.y = acc[i][1] + bi[1];
        o.z = acc[i][2] + bi[2]; o.w = acc[i][3] + bi[3];
        *(float4*)(C + (m0 + ty * 4 + i) * G3_ + n0 + tx * 4) = o;
    }
}

// One block per batch element; 384 threads; Whh held in VGPRs.
// Thread tid: output n = tid (n = g*4+c), k-chunk c = tid&3 (32 k values).
__global__ __launch_bounds__(384, 1) void gru_seq(const float* __restrict__ gi,
                                                  const float* __restrict__ Whh,
                                                  const float* __restrict__ bhh,
                                                  float* __restrict__ hout)
{
    __shared__ alignas(16) float h_s[4 * 36];   // 4 chunks of 32, padded to 36
    __shared__ float gh_s[G3_];
    __shared__ float gin_s[H_];

    const int tid = threadIdx.x;
    const int b = blockIdx.x;
    const int g = tid >> 2, c = tid & 3;

    // weights: rows g*4+j, cols [32c, 32c+32)
    float w[4][32];
    #pragma unroll
    for (int j = 0; j < 4; ++j) {
        const float4* wp = (const float4*)(Whh + (size_t)(g * 4 + j) * 128 + c * 32);
        #pragma unroll
        for (int q = 0; q < 8; ++q) {
            float4 v = wp[q];
            w[j][4 * q + 0] = v.x; w[j][4 * q + 1] = v.y;
            w[j][4 * q + 2] = v.z; w[j][4 * q + 3] = v.w;
        }
    }
    const float bhh_n = bhh[tid];

    if (tid < H_) h_s[36 * (tid >> 5) + (tid & 31)] = 0.f;
    __syncthreads();

    const float* gip = gi + (size_t)b * T_ * G3_;
    float* hop = hout + (size_t)b * T_ * H_;

    for (int t = 0; t < T_; ++t) {
        const float4* hv = (const float4*)(h_s + 36 * c);
        float px = 0.f, py = 0.f, pz = 0.f, pw = 0.f;
        #pragma unroll
        for (int q = 0; q < 8; ++q) {
            float4 h4 = hv[q];
            float hh[4] = {h4.x, h4.y, h4.z, h4.w};
            #pragma unroll
            for (int e = 0; e < 4; ++e) {
                px += w[0][4 * q + e] * hh[e];
                py += w[1][4 * q + e] * hh[e];
                pz += w[2][4 * q + e] * hh[e];
                pw += w[3][4 * q + e] * hh[e];
            }
        }
        px += __shfl_xor(px, 1); px += __shfl_xor(px, 2);
        py += __shfl_xor(py, 1); py += __shfl_xor(py, 2);
        pz += __shfl_xor(pz, 1); pz += __shfl_xor(pz, 2);
        pw += __shfl_xor(pw, 1); pw += __shfl_xor(pw, 2);
        float ghv = (c == 0) ? px : ((c == 1) ? py : ((c == 2) ? pz : pw));
        ghv += bhh_n;

        float giv = gip[(size_t)t * G3_ + tid];
        if (tid < 2 * H_) gh_s[tid] = ghv + giv;            // r, z: gi+gh combined
        else            { gh_s[tid] = ghv; gin_s[tid - 2 * H_] = giv; }
        __syncthreads();

        if (tid < H_) {
            float r = sigm(gh_s[tid]);
            float z = sigm(gh_s[H_ + tid]);
            float nn = tanh_f(gin_s[tid] + r * gh_s[2 * H_ + tid]);
            int hi = 36 * (tid >> 5) + (tid & 31);
            float hnew = (1.f - z) * nn + z * h_s[hi];
            h_s[hi] = hnew;
            hop[(size_t)t * H_ + tid] = hnew;
        }
        __syncthreads();
    }
}

// One wave per sample: a = h2·W1[reg] + b1[reg]; SiLU; corr = a·W2[reg] + b2[reg]
// out = lag_scale*x[...,0] + lag_bias + corr
__global__ __launch_bounds__(256) void head_k(const float* __restrict__ h2,
                                              const float* __restrict__ x,
                                              const int* __restrict__ regime,
                                              const float* __restrict__ W1,
                                              const float* __restrict__ b1,
                                              const float* __restrict__ W2,
                                              const float* __restrict__ b2,
                                              const float* __restrict__ lag_scale,
                                              const float* __restrict__ lag_bias,
                                              float* __restrict__ out)
{
    __shared__ alignas(16) float hrow[4][128];
    const int tid = threadIdx.x;
    const int wv = tid >> 6, lane = tid & 63;
    const size_t s = (size_t)blockIdx.x * 4 + wv;
    const int reg = regime[s];

    if (lane < 32)
        ((float4*)hrow[wv])[lane] = ((const float4*)(h2 + s * H_))[lane];
    __syncthreads();

    float acc = b1[reg * K_ + lane];
    const float* Wp = W1 + (size_t)reg * H_ * K_ + lane;
    const float4* h4p = (const float4*)hrow[wv];
    #pragma unroll
    for (int q = 0; q < 32; ++q) {
        float4 h4 = h4p[q];
        acc += h4.x * Wp[(4 * q + 0) * K_];
        acc += h4.y * Wp[(4 * q + 1) * K_];
        acc += h4.z * Wp[(4 * q + 2) * K_];
        acc += h4.w * Wp[(4 * q + 3) * K_];
    }
    float silu = acc * sigm(acc);
    float v = silu * W2[reg * K_ + lane];
    #pragma unroll
    for (int m = 1; m < 64; m <<= 1) v += __shfl_xor(v, m);
    if (lane == 0) {
        float lag = lag_scale[0] * x[s * F_] + lag_bias[0];
        out[s] = lag + v + b2[reg];
    }
}

extern "C" void kernel_launch(void* const* d_in, const int* in_sizes, int n_in,
                              void* d_out, int out_size, void* d_ws, size_t ws_size,
                              hipStream_t stream) {
    const float* x         = (const float*)d_in[0];
    const int*   regime    = (const int*)d_in[1];
    const float* lag_scale = (const float*)d_in[2];
    const float* lag_bias  = (const float*)d_in[3];
    const float* Wih0      = (const float*)d_in[4];
    const float* Whh0      = (const float*)d_in[5];
    const float* bih0      = (const float*)d_in[6];
    const float* bhh0      = (const float*)d_in[7];
    const float* Wih1      = (const float*)d_in[8];
    const float* Whh1      = (const float*)d_in[9];
    const float* bih1      = (const float*)d_in[10];
    const float* bhh1      = (const float*)d_in[11];
    const float* W1        = (const float*)d_in[12];
    const float* b1        = (const float*)d_in[13];
    const float* W2        = (const float*)d_in[14];
    const float* b2        = (const float*)d_in[15];
    float* out = (float*)d_out;

    const size_t NT = (size_t)B_ * T_;               // 131072
    const size_t need = NT * G3_ * 4 + NT * H_ * 4;  // 256 MiB
    if (ws_size < need) {
        // signal "workspace too small" with an absurd absmax
        hipMemsetAsync(d_out, 0x7F, (size_t)out_size * 4, stream);
        return;
    }
    float* gi = (float*)d_ws;
    float* hb = gi + NT * G3_;                       // h1, then reused as h2

    dim3 ggrid(G3_ / 64, (int)(NT / 64));            // (6, 2048)
    gemm_gi<<<ggrid, 256, 0, stream>>>(x, Wih0, bih0, gi);
    gru_seq<<<B_, 384, 0, stream>>>(gi, Whh0, bhh0, hb);
    gemm_gi<<<ggrid, 256, 0, stream>>>(hb, Wih1, bih1, gi);
    gru_seq<<<B_, 384, 0, stream>>>(gi, Whh1, bhh1, hb);
    head_k<<<(int)(NT / 4), 256, 0, stream>>>(hb, x, regime, W1, b1, W2, b2,
                                              lag_scale, lag_bias, out);
}

// Round 2
// 1294.645 us; speedup vs baseline: 1.3178x; 1.3178x over previous
//
#include <hip/hip_runtime.h>
#include <hip/hip_bf16.h>
#include <cstdint>

#define B_ 256
#define T_ 512
#define F_ 128
#define H_ 128
#define G3_ 384
#define R_ 8
#define K_ 64

__device__ __forceinline__ float sigm(float x) { return 1.f / (1.f + __expf(-x)); }
__device__ __forceinline__ float tanh_f(float x) { return 1.f - 2.f / (1.f + __expf(2.f * x)); }

// C[m][n] = sum_k A[m][k] * W[n][k] + bias[n];  M = B*T, N = 384, K = 128
__global__ __launch_bounds__(256) void gemm_gi(const float* __restrict__ A,
                                               const float* __restrict__ W,
                                               const float* __restrict__ bias,
                                               float* __restrict__ C)
{
    __shared__ alignas(16) float As[32][68];
    __shared__ alignas(16) float Bs[32][68];
    const int tid = threadIdx.x;
    const int tx = tid & 15, ty = tid >> 4;
    const size_t m0 = (size_t)blockIdx.y * 64;
    const int n0 = blockIdx.x * 64;

    float acc[4][4] = {};

    for (int kb = 0; kb < 128; kb += 32) {
        #pragma unroll
        for (int it = 0; it < 2; ++it) {
            int idx = tid + it * 256;
            int row = idx >> 3, kq = idx & 7;
            float4 av = *(const float4*)(A + (m0 + row) * 128 + kb + kq * 4);
            As[kq * 4 + 0][row] = av.x; As[kq * 4 + 1][row] = av.y;
            As[kq * 4 + 2][row] = av.z; As[kq * 4 + 3][row] = av.w;
            float4 bv = *(const float4*)(W + (size_t)(n0 + row) * 128 + kb + kq * 4);
            Bs[kq * 4 + 0][row] = bv.x; Bs[kq * 4 + 1][row] = bv.y;
            Bs[kq * 4 + 2][row] = bv.z; Bs[kq * 4 + 3][row] = bv.w;
        }
        __syncthreads();
        #pragma unroll
        for (int k = 0; k < 32; ++k) {
            float4 a4 = *(const float4*)&As[k][ty * 4];
            float4 b4 = *(const float4*)&Bs[k][tx * 4];
            float a_[4] = {a4.x, a4.y, a4.z, a4.w};
            float b_[4] = {b4.x, b4.y, b4.z, b4.w};
            #pragma unroll
            for (int i = 0; i < 4; ++i)
                #pragma unroll
                for (int j = 0; j < 4; ++j)
                    acc[i][j] += a_[i] * b_[j];
        }
        __syncthreads();
    }

    float4 bb = *(const float4*)(bias + n0 + tx * 4);
    float bi[4] = {bb.x, bb.y, bb.z, bb.w};
    #pragma unroll
    for (int i = 0; i < 4; ++i) {
        float4 o;
        o.x = acc[i][0] + bi[0]; o.y = acc[i][1] + bi[1];
        o.z = acc[i][2] + bi[2]; o.w = acc[i][3] + bi[3];
        *(float4*)(C + (m0 + ty * 4 + i) * G3_ + n0 + tx * 4) = o;
    }
}

// One block (512 threads, 8 waves) per batch element.
// Thread (w=tid>>6, lane): owns output j = 16w + (lane&15), k-chunk s = lane>>4.
// Each thread computes partials of ALL THREE gate rows (j, 128+j, 256+j) over
// its 32-k chunk; 2x shfl_xor reduces over s; lane<16 finalizes. h double-
// buffered in LDS -> ONE raw s_barrier per step (lgkmcnt-only drain: the
// per-step hout store and gi prefetch stay in flight across the barrier).
__global__ __launch_bounds__(512, 2) void gru_seq(const float* __restrict__ gi,
                                                  const float* __restrict__ Whh,
                                                  const float* __restrict__ bhh,
                                                  float* __restrict__ hout)
{
    // two h buffers, each 4 chunks of 32 floats padded to 36 (bank spread)
    __shared__ alignas(16) float hbuf[2][4 * 36];

    const int tid = threadIdx.x;
    const int b = blockIdx.x;
    const int w = tid >> 6, lane = tid & 63;
    const int j = 16 * w + (lane & 15);
    const int s = lane >> 4;

    // per-thread weights: rows j (r), 128+j (z), 256+j (n), cols [32s,32s+32)
    float wr[32], wz[32], wn[32];
    {
        const float4* p0 = (const float4*)(Whh + (size_t)j * 128 + s * 32);
        const float4* p1 = (const float4*)(Whh + (size_t)(128 + j) * 128 + s * 32);
        const float4* p2 = (const float4*)(Whh + (size_t)(256 + j) * 128 + s * 32);
        #pragma unroll
        for (int q = 0; q < 8; ++q) {
            float4 v0 = p0[q], v1 = p1[q], v2 = p2[q];
            wr[4*q+0]=v0.x; wr[4*q+1]=v0.y; wr[4*q+2]=v0.z; wr[4*q+3]=v0.w;
            wz[4*q+0]=v1.x; wz[4*q+1]=v1.y; wz[4*q+2]=v1.z; wz[4*q+3]=v1.w;
            wn[4*q+0]=v2.x; wn[4*q+1]=v2.y; wn[4*q+2]=v2.z; wn[4*q+3]=v2.w;
        }
    }
    const float br = bhh[j], bz = bhh[128 + j], bn = bhh[256 + j];

    if (tid < H_) hbuf[0][(tid >> 5) * 36 + (tid & 31)] = 0.f;
    __syncthreads();

    const float* gbase = gi + (size_t)b * T_ * G3_ + j;
    float* hop = hout + (size_t)b * T_ * H_;

    // prefetch t=0 gate inputs
    float gr = gbase[0], gz = gbase[128], gn = gbase[256];

    float hprev = 0.f;
    int p = 0;

    for (int t = 0; t < T_; ++t) {
        const float4* hv = (const float4*)(&hbuf[p][s * 36]);
        float pr = 0.f, pz = 0.f, pn = 0.f;
        #pragma unroll
        for (int q = 0; q < 8; ++q) {
            float4 h4 = hv[q];
            float hh[4] = {h4.x, h4.y, h4.z, h4.w};
            #pragma unroll
            for (int e = 0; e < 4; ++e) {
                pr += wr[4*q+e] * hh[e];
                pz += wz[4*q+e] * hh[e];
                pn += wn[4*q+e] * hh[e];
            }
        }
        // reduce over the 4 k-chunks (s): butterfly across lane groups 16, 32
        pr += __shfl_xor(pr, 16); pr += __shfl_xor(pr, 32);
        pz += __shfl_xor(pz, 16); pz += __shfl_xor(pz, 32);
        pn += __shfl_xor(pn, 16); pn += __shfl_xor(pn, 32);

        if (lane < 16) {
            float r  = sigm(gr + pr + br);
            float z  = sigm(gz + pz + bz);
            float nn = tanh_f(gn + r * (pn + bn));
            float hnew = (1.f - z) * nn + z * hprev;
            hprev = hnew;
            hbuf[p ^ 1][(j >> 5) * 36 + (j & 31)] = hnew;
            hop[(size_t)t * H_ + j] = hnew;   // fire-and-forget
        }

        // prefetch next step's gate inputs (fully hidden behind next matvec)
        {
            int tn = (t + 1 < T_) ? t + 1 : t;
            const float* gp = gbase + (size_t)tn * G3_;
            gr = gp[0]; gz = gp[128]; gn = gp[256];
        }

        // LDS-only drain + raw barrier: do NOT drain vmcnt (stores/prefetch
        // stay in flight). ds_write above is ordered by the memory clobber.
        asm volatile("s_waitcnt lgkmcnt(0)" ::: "memory");
        __builtin_amdgcn_s_barrier();
        p ^= 1;
    }
}

// One wave per sample: a = h2·W1[reg] + b1[reg]; SiLU; corr = a·W2[reg] + b2[reg]
__global__ __launch_bounds__(256) void head_k(const float* __restrict__ h2,
                                              const float* __restrict__ x,
                                              const int* __restrict__ regime,
                                              const float* __restrict__ W1,
                                              const float* __restrict__ b1,
                                              const float* __restrict__ W2,
                                              const float* __restrict__ b2,
                                              const float* __restrict__ lag_scale,
                                              const float* __restrict__ lag_bias,
                                              float* __restrict__ out)
{
    __shared__ alignas(16) float hrow[4][128];
    const int tid = threadIdx.x;
    const int wv = tid >> 6, lane = tid & 63;
    const size_t s = (size_t)blockIdx.x * 4 + wv;
    const int reg = regime[s];

    if (lane < 32)
        ((float4*)hrow[wv])[lane] = ((const float4*)(h2 + s * H_))[lane];
    __syncthreads();

    float acc = b1[reg * K_ + lane];
    const float* Wp = W1 + (size_t)reg * H_ * K_ + lane;
    const float4* h4p = (const float4*)hrow[wv];
    #pragma unroll
    for (int q = 0; q < 32; ++q) {
        float4 h4 = h4p[q];
        acc += h4.x * Wp[(4 * q + 0) * K_];
        acc += h4.y * Wp[(4 * q + 1) * K_];
        acc += h4.z * Wp[(4 * q + 2) * K_];
        acc += h4.w * Wp[(4 * q + 3) * K_];
    }
    float silu = acc * sigm(acc);
    float v = silu * W2[reg * K_ + lane];
    #pragma unroll
    for (int m = 1; m < 64; m <<= 1) v += __shfl_xor(v, m);
    if (lane == 0) {
        float lag = lag_scale[0] * x[s * F_] + lag_bias[0];
        out[s] = lag + v + b2[reg];
    }
}

extern "C" void kernel_launch(void* const* d_in, const int* in_sizes, int n_in,
                              void* d_out, int out_size, void* d_ws, size_t ws_size,
                              hipStream_t stream) {
    const float* x         = (const float*)d_in[0];
    const int*   regime    = (const int*)d_in[1];
    const float* lag_scale = (const float*)d_in[2];
    const float* lag_bias  = (const float*)d_in[3];
    const float* Wih0      = (const float*)d_in[4];
    const float* Whh0      = (const float*)d_in[5];
    const float* bih0      = (const float*)d_in[6];
    const float* bhh0      = (const float*)d_in[7];
    const float* Wih1      = (const float*)d_in[8];
    const float* Whh1      = (const float*)d_in[9];
    const float* bih1      = (const float*)d_in[10];
    const float* bhh1      = (const float*)d_in[11];
    const float* W1        = (const float*)d_in[12];
    const float* b1        = (const float*)d_in[13];
    const float* W2        = (const float*)d_in[14];
    const float* b2        = (const float*)d_in[15];
    float* out = (float*)d_out;

    const size_t NT = (size_t)B_ * T_;               // 131072
    const size_t need = NT * G3_ * 4 + NT * H_ * 4;  // 256 MiB
    if (ws_size < need) {
        hipMemsetAsync(d_out, 0x7F, (size_t)out_size * 4, stream);
        return;
    }
    float* gi = (float*)d_ws;
    float* hb = gi + NT * G3_;                       // h1, then reused as h2

    dim3 ggrid(G3_ / 64, (int)(NT / 64));            // (6, 2048)
    gemm_gi<<<ggrid, 256, 0, stream>>>(x, Wih0, bih0, gi);
    gru_seq<<<B_, 512, 0, stream>>>(gi, Whh0, bhh0, hb);
    gemm_gi<<<ggrid, 256, 0, stream>>>(hb, Wih1, bih1, gi);
    gru_seq<<<B_, 512, 0, stream>>>(gi, Whh1, bhh1, hb);
    head_k<<<(int)(NT / 4), 256, 0, stream>>>(hb, x, regime, W1, b1, W2, b2,
                                              lag_scale, lag_bias, out);
}